// Round 1
// baseline (139.523 us; speedup 1.0000x reference)
//
#include <hip/hip_runtime.h>
#include <hip/hip_bf16.h>

typedef __bf16 bf16x8 __attribute__((ext_vector_type(8)));
typedef float f32x4 __attribute__((ext_vector_type(4)));

#define B_DIM 16
#define L_DIM 1024
#define IN_DIM 128
#define H_DIM 4
#define C_DIM 32
#define HC 128
#define TI 32
#define ALPHA_STRIDE 1032  // 1024 + 8 bf16 pad -> 2064B row stride, 16B aligned, 2-way-only LDS conflict

// ---------------------------------------------------------------------------
// Kernel A: xp = x @ W.T + b  (fp32 accum), fused with:
//   - xpT[b,h,c,l] = bf16(xp)   (transposed for contiguous-K MFMA B-frags)
//   - a_src[b,h,l] = sum_c xp*att_src,  a_dst likewise (fp32, pre-rounding)
// ---------------------------------------------------------------------------
__global__ __launch_bounds__(256) void xp_proj_kernel(
    const float* __restrict__ x, const float* __restrict__ W,
    const float* __restrict__ bias, const float* __restrict__ att_src,
    const float* __restrict__ att_dst, __hip_bfloat16* __restrict__ xpT,
    float* __restrict__ a_src, float* __restrict__ a_dst)
{
  __shared__ float Wt[128 * 129];   // Wt[k*129 + n] = W[n][k], +1 pad: conflict-free
  __shared__ float xs[8][128];
  const int t = threadIdx.x;
  const int row0 = blockIdx.x * 8;  // global row over B*L

  for (int i = t; i < 128 * 128; i += 256) {
    const int n = i >> 7, k = i & 127;
    Wt[k * 129 + n] = W[i];
  }
  for (int i = t; i < 8 * 128; i += 256) {
    const int r = i >> 7, k = i & 127;
    xs[r][k] = x[(size_t)(row0 + r) * IN_DIM + k];
  }
  __syncthreads();

  const int n  = t & 127;   // output column (h*32+c)
  const int rg = t >> 7;    // row group 0/1 -> rows rg*4 .. rg*4+3
  float acc[4] = {0.f, 0.f, 0.f, 0.f};
  for (int k = 0; k < 128; ++k) {
    const float wv = Wt[k * 129 + n];
#pragma unroll
    for (int q = 0; q < 4; ++q)
      acc[q] = fmaf(xs[rg * 4 + q][k], wv, acc[q]);
  }
  const float bv = bias[n];
  const int h = n >> 5, c = n & 31;
  const float ws_ = att_src[n];   // flat (H*C): index n == h*32+c
  const float wd_ = att_dst[n];

#pragma unroll
  for (int q = 0; q < 4; ++q) {
    const float v = acc[q] + bv;
    const int grow = row0 + rg * 4 + q;
    const int bb = grow >> 10;
    const int l  = grow & 1023;
    // transposed bf16 store for PV
    xpT[((size_t)((bb * H_DIM + h) * C_DIM + c)) * L_DIM + l] = __float2bfloat16(v);
    // 32-lane (c-group) reductions for a_src / a_dst
    float s1 = v * ws_, s2 = v * wd_;
#pragma unroll
    for (int off = 16; off > 0; off >>= 1) {
      s1 += __shfl_xor(s1, off);
      s2 += __shfl_xor(s2, off);
    }
    if (c == 0) {
      a_src[((size_t)(bb * H_DIM + h)) * L_DIM + l] = s1;
      a_dst[((size_t)(bb * H_DIM + h)) * L_DIM + l] = s2;
    }
  }
}

// ---------------------------------------------------------------------------
// Kernel C: per (b, 32-row i-tile): adj->bitmask, then per head:
//   wave-parallel masked lrelu+softmax (2-pass, regs) -> bf16 alpha in LDS
//   PV: 4 waves x (16x16 quadrant) x 32 K-steps of mfma_f32_16x16x32_bf16
// ---------------------------------------------------------------------------
__global__ __launch_bounds__(256) void gat_attn_kernel(
    const int* __restrict__ adj, const __hip_bfloat16* __restrict__ xpT,
    const float* __restrict__ a_src, const float* __restrict__ a_dst,
    float* __restrict__ out)
{
  __shared__ __align__(16) __hip_bfloat16 alpha[TI][ALPHA_STRIDE];
  __shared__ unsigned int msk[TI][32];
  __shared__ float asrc_s[L_DIM];
  __shared__ float rscale[TI];

  const int b  = blockIdx.y;
  const int i0 = blockIdx.x * TI;
  const int t = threadIdx.x;
  const int wv = t >> 6;
  const int lane = t & 63;
  const int rbase = wv * 8;   // 8 rows per wave

  // ---- phase 0: adjacency -> bitmask (the HBM-bound read, once) ----
  for (int rr = 0; rr < 8; ++rr) {
    const int r = rbase + rr;
    const int* arow = adj + ((size_t)b * L_DIM + i0 + r) * L_DIM;
    for (int jc = 0; jc < 16; ++jc) {
      const int a = arow[jc * 64 + lane];
      const unsigned long long m = __ballot(a > 0);
      if (lane == 0) {
        msk[r][jc * 2]     = (unsigned)m;
        msk[r][jc * 2 + 1] = (unsigned)(m >> 32);
      }
    }
  }

  for (int h = 0; h < H_DIM; ++h) {
    __syncthreads();   // prev head's asrc_s/alpha readers done
    for (int idx = t; idx < L_DIM; idx += 256)
      asrc_s[idx] = a_src[((size_t)(b * H_DIM + h)) * L_DIM + idx];
    __syncthreads();

    // ---- scores + softmax: wave w owns rows rbase..rbase+7 ----
    for (int rr = 0; rr < 8; ++rr) {
      const int r = rbase + rr;
      const int i = i0 + r;
      const float d = a_dst[((size_t)(b * H_DIM + h)) * L_DIM + i];
      float sv[16];
      float mx = -INFINITY;
#pragma unroll
      for (int jc = 0; jc < 16; ++jc) {
        const int j = jc * 64 + lane;
        float s = asrc_s[j] + d;
        s = s > 0.0f ? s : 0.2f * s;
        const unsigned mword = msk[r][j >> 5];
        const bool keep = (((mword >> (j & 31)) & 1u) != 0u) || (j == i);
        s = keep ? s : -INFINITY;
        sv[jc] = s;
        mx = fmaxf(mx, s);
      }
#pragma unroll
      for (int off = 32; off > 0; off >>= 1) mx = fmaxf(mx, __shfl_xor(mx, off));
      float sum = 0.0f;
#pragma unroll
      for (int jc = 0; jc < 16; ++jc) {
        const float e = __expf(sv[jc] - mx);   // -inf -> 0
        sum += e;
        alpha[r][jc * 64 + lane] = __float2bfloat16(e);
      }
#pragma unroll
      for (int off = 32; off > 0; off >>= 1) sum += __shfl_xor(sum, off);
      if (lane == 0) rscale[r] = 1.0f / sum;
    }
    __syncthreads();

    // ---- PV: wave -> quadrant (mr,nc); A from LDS, B direct from L2 xpT ----
    const int mr = wv >> 1;
    const int nc = wv & 1;
    const int lrow = lane & 15;
    const int lk = (lane >> 4) * 8;
    f32x4 acc = {0.f, 0.f, 0.f, 0.f};
    const __hip_bfloat16* xb =
        xpT + ((size_t)((b * H_DIM + h) * C_DIM + nc * 16 + lrow)) * L_DIM;
    const __hip_bfloat16* ar = &alpha[mr * 16 + lrow][0];
#pragma unroll 4
    for (int k0 = 0; k0 < L_DIM; k0 += 32) {
      const bf16x8 af = *reinterpret_cast<const bf16x8*>(ar + k0 + lk);
      const bf16x8 bfv = *reinterpret_cast<const bf16x8*>(xb + k0 + lk);
      acc = __builtin_amdgcn_mfma_f32_16x16x32_bf16(af, bfv, acc, 0, 0, 0);
    }
    // D layout: col = lane&15, row = (lane>>4)*4 + reg  [m89-verified]
#pragma unroll
    for (int rgi = 0; rgi < 4; ++rgi) {
      const int row = mr * 16 + (lane >> 4) * 4 + rgi;
      const int col = nc * 16 + lrow;
      out[((size_t)(b * L_DIM + i0 + row)) * HC + h * C_DIM + col] =
          acc[rgi] * rscale[row];
    }
  }
}

extern "C" void kernel_launch(void* const* d_in, const int* in_sizes, int n_in,
                              void* d_out, int out_size, void* d_ws, size_t ws_size,
                              hipStream_t stream) {
  (void)in_sizes; (void)n_in; (void)out_size; (void)ws_size;
  const float* x        = (const float*)d_in[0];
  const int*   adj      = (const int*)d_in[1];
  const float* W        = (const float*)d_in[2];
  const float* bias     = (const float*)d_in[3];
  const float* att_src  = (const float*)d_in[4];
  const float* att_dst  = (const float*)d_in[5];
  float* out = (float*)d_out;

  char* ws = (char*)d_ws;
  __hip_bfloat16* xpT = (__hip_bfloat16*)ws;                        // 4 MiB
  float* a_src = (float*)(ws + (size_t)4 * 1024 * 1024);            // 256 KiB
  float* a_dst = (float*)(ws + (size_t)4 * 1024 * 1024 + 262144);   // 256 KiB

  hipLaunchKernelGGL(xp_proj_kernel, dim3((B_DIM * L_DIM) / 8), dim3(256), 0, stream,
                     x, W, bias, att_src, att_dst, xpT, a_src, a_dst);
  hipLaunchKernelGGL(gat_attn_kernel, dim3(L_DIM / TI, B_DIM), dim3(256), 0, stream,
                     adj, xpT, a_src, a_dst, out);
}

// Round 2
// 106.747 us; speedup vs baseline: 1.3070x; 1.3070x over previous
//
#include <hip/hip_runtime.h>
#include <hip/hip_bf16.h>

typedef __bf16 bf16x8 __attribute__((ext_vector_type(8)));
typedef float f32x4 __attribute__((ext_vector_type(4)));
typedef float f32x16 __attribute__((ext_vector_type(16)));

#define B_DIM 16
#define L_DIM 1024
#define IN_DIM 128
#define H_DIM 4
#define C_DIM 32
#define HC 128
#define TI 32
#define LOG2E 1.4426950408889634f

// ---------------------------------------------------------------------------
// Kernel A: xp = x @ W.T + b  (fp32 accum), fused with:
//   - xpT[b,h,c,l] = bf16(xp)   (transposed for contiguous-K MFMA B-frags)
//   - a_src/a_dst[b,h,l] (fp32, pre-rounding), PRE-SCALED by log2(e) so the
//     attention hot loop can use raw v_exp_f32 (2^x). lrelu commutes with
//     positive scaling: lrelu(log2e*s) == log2e*lrelu(s).
// ---------------------------------------------------------------------------
__global__ __launch_bounds__(256) void xp_proj_kernel(
    const float* __restrict__ x, const float* __restrict__ W,
    const float* __restrict__ bias, const float* __restrict__ att_src,
    const float* __restrict__ att_dst, __hip_bfloat16* __restrict__ xpT,
    float* __restrict__ a_src, float* __restrict__ a_dst)
{
  __shared__ float Wt[128 * 129];   // Wt[k*129 + n] = W[n][k], +1 pad: conflict-free
  __shared__ float xs[8][128];
  const int t = threadIdx.x;
  const int row0 = blockIdx.x * 8;  // global row over B*L

  for (int i = t; i < 128 * 128; i += 256) {
    const int n = i >> 7, k = i & 127;
    Wt[k * 129 + n] = W[i];
  }
  for (int i = t; i < 8 * 128; i += 256) {
    const int r = i >> 7, k = i & 127;
    xs[r][k] = x[(size_t)(row0 + r) * IN_DIM + k];
  }
  __syncthreads();

  const int n  = t & 127;   // output column (h*32+c)
  const int rg = t >> 7;    // row group 0/1 -> rows rg*4 .. rg*4+3
  float acc[4] = {0.f, 0.f, 0.f, 0.f};
  for (int k = 0; k < 128; ++k) {
    const float wv = Wt[k * 129 + n];
#pragma unroll
    for (int q = 0; q < 4; ++q)
      acc[q] = fmaf(xs[rg * 4 + q][k], wv, acc[q]);
  }
  const float bv = bias[n];
  const int h = n >> 5, c = n & 31;
  const float ws_ = att_src[n];   // flat (H*C): index n == h*32+c
  const float wd_ = att_dst[n];

#pragma unroll
  for (int q = 0; q < 4; ++q) {
    const float v = acc[q] + bv;
    const int grow = row0 + rg * 4 + q;
    const int bb = grow >> 10;
    const int l  = grow & 1023;
    // transposed bf16 store for PV
    xpT[((size_t)((bb * H_DIM + h) * C_DIM + c)) * L_DIM + l] = __float2bfloat16(v);
    // 32-lane (c-group) reductions for a_src / a_dst
    float s1 = v * ws_, s2 = v * wd_;
#pragma unroll
    for (int off = 16; off > 0; off >>= 1) {
      s1 += __shfl_xor(s1, off);
      s2 += __shfl_xor(s2, off);
    }
    if (c == 0) {
      a_src[((size_t)(bb * H_DIM + h)) * L_DIM + l] = s1 * LOG2E;
      a_dst[((size_t)(bb * H_DIM + h)) * L_DIM + l] = s2 * LOG2E;
    }
  }
}

// ---------------------------------------------------------------------------
// Kernel C (flash, barrier-free main loop):
//   block = (i-tile, b), 4 waves, wave w == head w.
//   Phase 0 (cooperative): adj rows -> bitmask LDS (diagonal folded in),
//                          asrc for own head -> LDS.  ONE __syncthreads.
//   Main loop per wave: 64 chunks of K=16. Lane l computes 8 scores for
//   row l&31, k = k0 + (l>>5)*8 + e  == exactly the 32x32x16 A-fragment
//   layout. exp2 (inputs pre-scaled), mask select, bf16 pack, MFMA from
//   registers. No softmax max-pass (scores bounded, f32 can't overflow).
//   Epilogue: row-sum via shfl_xor(32), reciprocal gather via bpermute.
// ---------------------------------------------------------------------------
__global__ __launch_bounds__(256) void gat_attn_kernel(
    const int* __restrict__ adj, const __hip_bfloat16* __restrict__ xpT,
    const float* __restrict__ a_src, const float* __restrict__ a_dst,
    float* __restrict__ out)
{
  __shared__ unsigned int msk[TI][34];       // [row][word], stride 34: 2-way (free), b64-aligned
  __shared__ float asrc_s[H_DIM][L_DIM];     // 16 KB, per-head pre-scaled a_src

  const int b  = blockIdx.y;
  const int i0 = blockIdx.x * TI;
  const int t = threadIdx.x;
  const int wv = t >> 6;       // wave == head
  const int lane = t & 63;

  // ---- phase 0a: adjacency -> bitmask (wave w stages rows w*8..w*8+7) ----
  for (int rr = 0; rr < 8; ++rr) {
    const int r = wv * 8 + rr;
    const int i = i0 + r;
    const int* arow = adj + ((size_t)b * L_DIM + i) * L_DIM;
#pragma unroll 4
    for (int it = 0; it < 16; ++it) {
      const int j = it * 64 + lane;
      const int a = arow[j];
      const unsigned long long m = __ballot((a > 0) || (j == i));  // diag folded in
      if (lane == 0)
        *reinterpret_cast<unsigned long long*>(&msk[r][it * 2]) = m;
    }
  }
  // ---- phase 0b: asrc for own head (vectorized, 16B/lane) ----
  {
    const float* ap = a_src + ((size_t)(b * H_DIM + wv)) * L_DIM;
#pragma unroll
    for (int it = 0; it < 4; ++it) {
      const int idx = it * 256 + lane * 4;
      *reinterpret_cast<f32x4*>(&asrc_s[wv][idx]) =
          *reinterpret_cast<const f32x4*>(ap + idx);
    }
  }
  __syncthreads();   // the only block-wide barrier

  // ---- flash main loop: wave wv handles head wv, all 32 rows x 32 cols ----
  const int h = wv;
  const int lc = lane & 31;        // A-row == B-col == l&31
  const int khalf = lane >> 5;     // k-half selector
  const float dRow = a_dst[((size_t)(b * H_DIM + h)) * L_DIM + i0 + lc];
  const __hip_bfloat16* xb =
      xpT + ((size_t)((b * H_DIM + h) * C_DIM + lc)) * L_DIM;
  const float* asp = &asrc_s[h][0];

  f32x16 acc = {};
  float ssum = 0.0f;

  bf16x8 bnext = *reinterpret_cast<const bf16x8*>(xb + khalf * 8);  // prefetch chunk 0
  for (int k0 = 0; k0 < L_DIM; k0 += 16) {
    const int kb = k0 + khalf * 8;
    const bf16x8 bcur = bnext;
    if (k0 + 16 < L_DIM)
      bnext = *reinterpret_cast<const bf16x8*>(xb + kb + 16);

    const f32x4 a0 = *reinterpret_cast<const f32x4*>(asp + kb);
    const f32x4 a1 = *reinterpret_cast<const f32x4*>(asp + kb + 4);
    const unsigned word = msk[lc][k0 >> 5];
    const unsigned mbits = (word >> ((k0 & 16) + khalf * 8)) & 0xffu;

    bf16x8 afrag;
#pragma unroll
    for (int e = 0; e < 8; ++e) {
      const float av = (e < 4) ? a0[e & 3] : a1[e & 3];
      float sv = av + dRow;                       // log2e-scaled score
      sv = fmaxf(sv, 0.2f * sv);                  // leaky relu
      float ex = __builtin_amdgcn_exp2f(sv);      // exp(s) == 2^(log2e*s)
      ex = ((mbits >> e) & 1u) ? ex : 0.0f;       // mask (diag already in bits)
      ssum += ex;
      afrag[e] = (__bf16)ex;
    }
    acc = __builtin_amdgcn_mfma_f32_32x32x16_bf16(afrag, bcur, acc, 0, 0, 0);
  }

  // ---- epilogue: normalize + store ----
  const float stot = ssum + __shfl_xor(ssum, 32);   // lanes lc & lc+32 share row lc
  const float rinv = 1.0f / stot;                   // this lane's row reciprocal
#pragma unroll
  for (int reg = 0; reg < 16; ++reg) {
    const int tr = (reg & 3) + 8 * (reg >> 2) + 4 * khalf;  // D-row for this reg
    const float rs = __shfl(rinv, tr);             // row tr's reciprocal (lane tr < 32)
    out[((size_t)(b * L_DIM + i0 + tr)) * HC + h * C_DIM + lc] = acc[reg] * rs;
  }
}

extern "C" void kernel_launch(void* const* d_in, const int* in_sizes, int n_in,
                              void* d_out, int out_size, void* d_ws, size_t ws_size,
                              hipStream_t stream) {
  (void)in_sizes; (void)n_in; (void)out_size; (void)ws_size;
  const float* x        = (const float*)d_in[0];
  const int*   adj      = (const int*)d_in[1];
  const float* W        = (const float*)d_in[2];
  const float* bias     = (const float*)d_in[3];
  const float* att_src  = (const float*)d_in[4];
  const float* att_dst  = (const float*)d_in[5];
  float* out = (float*)d_out;

  char* ws = (char*)d_ws;
  __hip_bfloat16* xpT = (__hip_bfloat16*)ws;                        // 4 MiB
  float* a_src = (float*)(ws + (size_t)4 * 1024 * 1024);            // 256 KiB
  float* a_dst = (float*)(ws + (size_t)4 * 1024 * 1024 + 262144);   // 256 KiB

  hipLaunchKernelGGL(xp_proj_kernel, dim3((B_DIM * L_DIM) / 8), dim3(256), 0, stream,
                     x, W, bias, att_src, att_dst, xpT, a_src, a_dst);
  hipLaunchKernelGGL(gat_attn_kernel, dim3(L_DIM / TI, B_DIM), dim3(256), 0, stream,
                     adj, xpT, a_src, a_dst, out);
}

// Round 3
// 84.840 us; speedup vs baseline: 1.6445x; 1.2582x over previous
//
#include <hip/hip_runtime.h>
#include <hip/hip_bf16.h>

typedef __bf16 bf16x8 __attribute__((ext_vector_type(8)));
typedef float f32x4 __attribute__((ext_vector_type(4)));

#define B_DIM 16
#define L_DIM 1024
#define H_DIM 4
#define C_DIM 32
#define HC 128
#define TI 16

// ---------------------------------------------------------------------------
// Kernel A: xp = x @ W.T + b (fp32), fused with:
//   - xpT[b,h,c,l] = bf16(xp)     (transposed: contiguous-K MFMA B-frags)
//   - E1[b,h,l] = exp(a_src),  E2 = exp(0.2*a_src),  Rr = exp(-0.8*a_dst)
// Separable-exp trick: exp(lrelu(a+d)-d) = max(E1[j], E2[j]*Rr[i]);
// the exp(d_i) row factor cancels in softmax. O(L) exps, none in the L^2 loop.
// ---------------------------------------------------------------------------
__global__ __launch_bounds__(256) void xp_proj_kernel(
    const float* __restrict__ x, const float* __restrict__ W,
    const float* __restrict__ bias, const float* __restrict__ att_src,
    const float* __restrict__ att_dst, __hip_bfloat16* __restrict__ xpT,
    float* __restrict__ E1, float* __restrict__ E2, float* __restrict__ Rr)
{
  __shared__ float Wt[128 * 129];   // Wt[k*129+n] = W[n][k]; +1 pad: conflict-free
  __shared__ float xsT[128][16];    // xsT[k][r]; reads are wave-broadcast
  const int t = threadIdx.x;
  const int row0 = blockIdx.x * TI;

  for (int i = t; i < 128 * 128; i += 256) {
    const int n = i >> 7, k = i & 127;
    Wt[k * 129 + n] = W[i];
  }
  {
    const int r = t >> 4, kc = (t & 15) * 8;
    const float* xr = x + (size_t)(row0 + r) * 128 + kc;
    const f32x4 v0 = *reinterpret_cast<const f32x4*>(xr);
    const f32x4 v1 = *reinterpret_cast<const f32x4*>(xr + 4);
#pragma unroll
    for (int q = 0; q < 4; ++q) {
      xsT[kc + q][r] = v0[q];
      xsT[kc + 4 + q][r] = v1[q];
    }
  }
  __syncthreads();

  const int n  = t & 127;   // output column (h*32+c)
  const int rg = t >> 7;    // row-group: rows rg*8 .. rg*8+7
  float acc[8] = {0.f, 0.f, 0.f, 0.f, 0.f, 0.f, 0.f, 0.f};
  for (int k = 0; k < 128; ++k) {
    const float wv = Wt[k * 129 + n];
    const f32x4 xa = *reinterpret_cast<const f32x4*>(&xsT[k][rg * 8]);
    const f32x4 xb = *reinterpret_cast<const f32x4*>(&xsT[k][rg * 8 + 4]);
#pragma unroll
    for (int q = 0; q < 4; ++q) {
      acc[q]     = fmaf(xa[q], wv, acc[q]);
      acc[q + 4] = fmaf(xb[q], wv, acc[q + 4]);
    }
  }
  const float bv = bias[n];
  const int h = n >> 5, c = n & 31;
  const float ws_ = att_src[n];
  const float wd_ = att_dst[n];

#pragma unroll
  for (int q = 0; q < 8; ++q) {
    const float v = acc[q] + bv;
    const int grow = row0 + rg * 8 + q;
    const int bb = grow >> 10;
    const int l  = grow & 1023;
    xpT[((size_t)((bb * H_DIM + h) * C_DIM + c)) * L_DIM + l] = __float2bfloat16(v);
    float s1 = v * ws_, s2 = v * wd_;
#pragma unroll
    for (int off = 16; off > 0; off >>= 1) {
      s1 += __shfl_xor(s1, off);
      s2 += __shfl_xor(s2, off);
    }
    if (c == 0) {
      const size_t o = ((size_t)(bb * H_DIM + h)) * L_DIM + l;
      E1[o] = __expf(s1);
      E2[o] = __expf(0.2f * s1);
      Rr[o] = __expf(-0.8f * s2);
    }
  }
}

// ---------------------------------------------------------------------------
// Kernel C (flash, transcendental-free):
//   block = (16-row i-tile, b) via XCD-grouped decode; 4 waves, wave = head.
//   Phase 0: adj rows -> bitmask (diag folded), E1/E2 head-slices -> LDS.
//   Main: 32 iters of K=32; lane computes 8 scores max(E1, E2*Rrow), mask,
//   sum, bf16-pack == 16x16x32 A-frag; 2 MFMAs (channel halves) per iter.
//   Epilogue: row-sum shfl reduce, reciprocal, normalize on store.
// ---------------------------------------------------------------------------
__global__ __launch_bounds__(256) void gat_attn_kernel(
    const int* __restrict__ adj, const __hip_bfloat16* __restrict__ xpT,
    const float* __restrict__ E1, const float* __restrict__ E2,
    const float* __restrict__ Rr, float* __restrict__ out)
{
  __shared__ unsigned int msk[TI][34];   // stride 34: conflict-free reads
  __shared__ float e1s[H_DIM][L_DIM];    // 16 KB
  __shared__ float e2s[H_DIM][L_DIM];    // 16 KB

  // XCD-grouped decode: 2 b's per XCD -> xpT/E slices L2-resident
  const int wg  = blockIdx.x;
  const int xcd = wg & 7;
  const int idx = wg >> 3;
  const int b   = xcd * 2 + (idx & 1);
  const int i0  = (idx >> 1) * TI;

  const int t = threadIdx.x;
  const int wv = t >> 6;       // wave == head
  const int lane = t & 63;

  // ---- phase 0a: adjacency -> bitmask (wave w stages rows w*4..w*4+3) ----
#pragma unroll
  for (int rr = 0; rr < 4; ++rr) {
    const int r = wv * 4 + rr;
    const int i = i0 + r;
    const int* arow = adj + ((size_t)b * L_DIM + i) * L_DIM;
#pragma unroll 4
    for (int it = 0; it < 16; ++it) {
      const int j = it * 64 + lane;
      const unsigned long long m = __ballot((arow[j] > 0) || (j == i));
      if (lane == 0)
        *reinterpret_cast<unsigned long long*>(&msk[r][it * 2]) = m;
    }
  }
  // ---- phase 0b: E1/E2 head-slices -> LDS (16B/lane) ----
  {
    const float* p1 = E1 + ((size_t)(b * H_DIM + wv)) * L_DIM;
    const float* p2 = E2 + ((size_t)(b * H_DIM + wv)) * L_DIM;
#pragma unroll
    for (int it = 0; it < 4; ++it) {
      const int ix = it * 256 + lane * 4;
      *reinterpret_cast<f32x4*>(&e1s[wv][ix]) = *reinterpret_cast<const f32x4*>(p1 + ix);
      *reinterpret_cast<f32x4*>(&e2s[wv][ix]) = *reinterpret_cast<const f32x4*>(p2 + ix);
    }
  }
  __syncthreads();   // the only barrier

  // ---- flash main loop ----
  const int h = wv;
  const int ln15 = lane & 15;      // A-row == B-col
  const int kh = lane >> 4;        // k-group 0..3
  const int jb = kh * 8;           // k-offset within 32-chunk
  const float Rrow = Rr[((size_t)(b * H_DIM + h)) * L_DIM + i0 + ln15];
  const __hip_bfloat16* xb0 =
      xpT + ((size_t)((b * H_DIM + h) * C_DIM + ln15)) * L_DIM;
  const __hip_bfloat16* xb1 = xb0 + 16 * L_DIM;
  const float* p1 = &e1s[h][0];
  const float* p2 = &e2s[h][0];

  f32x4 acc0 = {0.f, 0.f, 0.f, 0.f};
  f32x4 acc1 = {0.f, 0.f, 0.f, 0.f};
  float ssum = 0.0f;

  bf16x8 b0n = *reinterpret_cast<const bf16x8*>(xb0 + jb);
  bf16x8 b1n = *reinterpret_cast<const bf16x8*>(xb1 + jb);
#pragma unroll 4
  for (int k0 = 0; k0 < L_DIM; k0 += 32) {
    const bf16x8 bb0 = b0n;
    const bf16x8 bb1 = b1n;
    // unguarded prefetch: final over-read lands in ws (E-arrays), safe
    b0n = *reinterpret_cast<const bf16x8*>(xb0 + k0 + 32 + jb);
    b1n = *reinterpret_cast<const bf16x8*>(xb1 + k0 + 32 + jb);

    const f32x4 ea = *reinterpret_cast<const f32x4*>(p1 + k0 + jb);
    const f32x4 eb = *reinterpret_cast<const f32x4*>(p1 + k0 + jb + 4);
    const f32x4 fa = *reinterpret_cast<const f32x4*>(p2 + k0 + jb);
    const f32x4 fb = *reinterpret_cast<const f32x4*>(p2 + k0 + jb + 4);
    const unsigned mb = (msk[ln15][k0 >> 5] >> jb) & 0xffu;

    bf16x8 af;
#pragma unroll
    for (int e = 0; e < 8; ++e) {
      const float e1v = (e < 4) ? ea[e & 3] : eb[e & 3];
      const float e2v = (e < 4) ? fa[e & 3] : fb[e & 3];
      float v = fmaxf(e1v, e2v * Rrow);          // exp(lrelu(s) - d_i)
      v = ((mb >> e) & 1u) ? v : 0.0f;           // adjacency mask (diag folded)
      ssum += v;
      af[e] = (__bf16)v;
    }
    acc0 = __builtin_amdgcn_mfma_f32_16x16x32_bf16(af, bb0, acc0, 0, 0, 0);
    acc1 = __builtin_amdgcn_mfma_f32_16x16x32_bf16(af, bb1, acc1, 0, 0, 0);
  }

  // ---- epilogue: row-sum, normalize, store ----
  ssum += __shfl_xor(ssum, 16);
  ssum += __shfl_xor(ssum, 32);      // all lanes: total for row ln15
  const float rinv = 1.0f / ssum;
#pragma unroll
  for (int reg = 0; reg < 4; ++reg) {
    const int row = kh * 4 + reg;                // D-row for this reg
    const float rs = __shfl(rinv, row);          // lane 'row' holds that row's rinv
    float* op = out + ((size_t)(b * L_DIM + i0 + row)) * HC + h * C_DIM;
    op[ln15]      = acc0[reg] * rs;
    op[16 + ln15] = acc1[reg] * rs;
  }
}

extern "C" void kernel_launch(void* const* d_in, const int* in_sizes, int n_in,
                              void* d_out, int out_size, void* d_ws, size_t ws_size,
                              hipStream_t stream) {
  (void)in_sizes; (void)n_in; (void)out_size; (void)ws_size;
  const float* x        = (const float*)d_in[0];
  const int*   adj      = (const int*)d_in[1];
  const float* W        = (const float*)d_in[2];
  const float* bias     = (const float*)d_in[3];
  const float* att_src  = (const float*)d_in[4];
  const float* att_dst  = (const float*)d_in[5];
  float* out = (float*)d_out;

  char* ws = (char*)d_ws;
  __hip_bfloat16* xpT = (__hip_bfloat16*)ws;                 // 4 MiB
  float* E1 = (float*)(ws + (size_t)4 * 1024 * 1024);        // 256 KiB
  float* E2 = (float*)(ws + (size_t)4 * 1024 * 1024 + 262144);
  float* Rr = (float*)(ws + (size_t)4 * 1024 * 1024 + 524288);

  hipLaunchKernelGGL(xp_proj_kernel, dim3((B_DIM * L_DIM) / TI), dim3(256), 0, stream,
                     x, W, bias, att_src, att_dst, xpT, E1, E2, Rr);
  hipLaunchKernelGGL(gat_attn_kernel, dim3((B_DIM * L_DIM) / TI), dim3(256), 0, stream,
                     adj, xpT, E1, E2, Rr, out);
}

// Round 4
// 70.674 us; speedup vs baseline: 1.9742x; 1.2004x over previous
//
#include <hip/hip_runtime.h>
#include <hip/hip_bf16.h>

typedef __bf16 bf16x8 __attribute__((ext_vector_type(8)));
typedef float f32x4 __attribute__((ext_vector_type(4)));

#define B_DIM 16
#define L_DIM 1024
#define H_DIM 4
#define C_DIM 32
#define HC 128
#define TI 16
#define MASK_PITCH 128   // bytes per (b,i) row of packed adjacency

// ---------------------------------------------------------------------------
// Kernel A: projection + E-factors + adj bit-packing, fused.
//   xp = x @ W.T + b (fp32 FMA core, LDS-staged W)
//   xpT[b,h,c,l] = bf16(xp)                      (MFMA-B-friendly transpose)
//   E1 = exp(a_src), E2 = exp(0.2 a_src), Rr = exp(-0.8 a_dst)   (O(L) exps)
//   mask_g[b,i, j/8] = adjacency bits (diag folded in)
// The 16 adj dwordx4 loads per thread are issued AFTER the barrier and
// BEFORE the FMA loop: no vmem in the loop, so they stay in flight under
// ~5us of compute (real MLP: 4KB/wave outstanding, no ballot serialization).
// ---------------------------------------------------------------------------
__global__ __launch_bounds__(256) void proj_mask_kernel(
    const float* __restrict__ x, const float* __restrict__ W,
    const float* __restrict__ bias, const float* __restrict__ att_src,
    const float* __restrict__ att_dst, const int* __restrict__ adj,
    __hip_bfloat16* __restrict__ xpT, float* __restrict__ E1,
    float* __restrict__ E2, float* __restrict__ Rr,
    unsigned char* __restrict__ mask_g)
{
  __shared__ float Wt[128 * 129];   // Wt[k*129+n] = W[n][k]; +1 pad
  __shared__ float xsT[128][16];    // xsT[k][r]
  const int t = threadIdx.x;
  const int row0 = blockIdx.x * TI;
  const int b  = row0 >> 10;
  const int i0 = row0 & 1023;

  for (int i = t; i < 128 * 128; i += 256) {
    const int n = i >> 7, k = i & 127;
    Wt[k * 129 + n] = W[i];
  }
  {
    const int r = t >> 4, kc = (t & 15) * 8;
    const float* xr = x + (size_t)(row0 + r) * 128 + kc;
    const f32x4 v0 = *reinterpret_cast<const f32x4*>(xr);
    const f32x4 v1 = *reinterpret_cast<const f32x4*>(xr + 4);
#pragma unroll
    for (int q = 0; q < 4; ++q) {
      xsT[kc + q][r] = v0[q];
      xsT[kc + 4 + q][r] = v1[q];
    }
  }
  __syncthreads();

  // ---- issue adj loads now; consumed only after the FMA loop ----
  const int ar  = t >> 4;          // row 0..15 within tile
  const int seg = t & 15;          // 64-j segment
  const int gi  = i0 + ar;
  const int* ap = adj + ((size_t)b * L_DIM + gi) * L_DIM + seg * 64;
  int4 av[16];
#pragma unroll
  for (int q = 0; q < 16; ++q)
    av[q] = *reinterpret_cast<const int4*>(ap + q * 4);

  // ---- FMA core (LDS only; adj loads in flight underneath) ----
  const int n  = t & 127;   // output column (h*32+c)
  const int rg = t >> 7;    // rows rg*8 .. rg*8+7
  float acc[8] = {0.f, 0.f, 0.f, 0.f, 0.f, 0.f, 0.f, 0.f};
  for (int k = 0; k < 128; ++k) {
    const float wv = Wt[k * 129 + n];
    const f32x4 xa = *reinterpret_cast<const f32x4*>(&xsT[k][rg * 8]);
    const f32x4 xb = *reinterpret_cast<const f32x4*>(&xsT[k][rg * 8 + 4]);
#pragma unroll
    for (int q = 0; q < 4; ++q) {
      acc[q]     = fmaf(xa[q], wv, acc[q]);
      acc[q + 4] = fmaf(xb[q], wv, acc[q + 4]);
    }
  }
  const float bv = bias[n];
  const int h = n >> 5, c = n & 31;
  const float ws_ = att_src[n];
  const float wd_ = att_dst[n];

#pragma unroll
  for (int q = 0; q < 8; ++q) {
    const float v = acc[q] + bv;
    const int grow = row0 + rg * 8 + q;
    const int bb = grow >> 10;
    const int l  = grow & 1023;
    xpT[((size_t)((bb * H_DIM + h) * C_DIM + c)) * L_DIM + l] = __float2bfloat16(v);
    float s1 = v * ws_, s2 = v * wd_;
#pragma unroll
    for (int off = 16; off > 0; off >>= 1) {
      s1 += __shfl_xor(s1, off);
      s2 += __shfl_xor(s2, off);
    }
    if (c == 0) {
      const size_t o = ((size_t)(bb * H_DIM + h)) * L_DIM + l;
      E1[o] = __expf(s1);
      E2[o] = __expf(0.2f * s1);
      Rr[o] = __expf(-0.8f * s2);
    }
  }

  // ---- pack adjacency bits (values are exactly {0,1}) ----
  unsigned lo = 0u, hi = 0u;
#pragma unroll
  for (int bq = 0; bq < 8; ++bq) {
    const int4 u = av[2 * bq], w = av[2 * bq + 1];
    unsigned bbits = (unsigned)u.x | ((unsigned)u.y << 1) |
                     ((unsigned)u.z << 2) | ((unsigned)u.w << 3) |
                     ((unsigned)w.x << 4) | ((unsigned)w.y << 5) |
                     ((unsigned)w.z << 6) | ((unsigned)w.w << 7);
    const int j0 = seg * 64 + bq * 8;
    const unsigned d = (unsigned)(gi - j0);
    if (d < 8u) bbits |= (1u << d);          // diagonal folded in
    if (bq < 4) lo |= bbits << (8 * bq);
    else        hi |= bbits << (8 * (bq - 4));
  }
  *reinterpret_cast<uint2*>(mask_g + ((size_t)b * L_DIM + gi) * MASK_PITCH + seg * 8) =
      make_uint2(lo, hi);
}

// ---------------------------------------------------------------------------
// Kernel C (flash): block = (16-row tile, b) XCD-grouped; wave = head.
//   Phase 0: 8B mask + E slices -> LDS (trivial, fully parallel loads).
//   Main: 32 iters of K=32: P = max(E1, E2*R) masked -> bf16 A-frag;
//         3 MFMAs: 2 channel halves + ones-B row-sum accumulator.
//   Epilogue: rs = 1/accS[reg] (lane-local, no shuffles), normalized store.
// ---------------------------------------------------------------------------
__global__ __launch_bounds__(256) void gat_attn_kernel(
    const unsigned char* __restrict__ mask_g,
    const __hip_bfloat16* __restrict__ xpT, const float* __restrict__ E1,
    const float* __restrict__ E2, const float* __restrict__ Rr,
    float* __restrict__ out)
{
  __shared__ __align__(8) unsigned char msk_b[TI][136];  // 136 = 34 words: conflict-free
  __shared__ float e1s[H_DIM][L_DIM];    // 16 KB
  __shared__ float e2s[H_DIM][L_DIM];    // 16 KB

  // XCD-grouped decode: 2 b's per XCD -> xpT/E/mask slices L2-resident
  const int wg  = blockIdx.x;
  const int xcd = wg & 7;
  const int idx = wg >> 3;
  const int b   = xcd * 2 + (idx & 1);
  const int i0  = (idx >> 1) * TI;

  const int t = threadIdx.x;
  const int wv = t >> 6;       // wave == head
  const int lane = t & 63;

  // ---- phase 0a: mask bytes -> LDS (one uint2 per thread) ----
  {
    const int r = t >> 4, sg = t & 15;
    const uint2 m = *reinterpret_cast<const uint2*>(
        mask_g + ((size_t)b * L_DIM + i0 + r) * MASK_PITCH + sg * 8);
    *reinterpret_cast<uint2*>(&msk_b[r][sg * 8]) = m;
  }
  // ---- phase 0b: E1/E2 head-slices -> LDS (16B/lane) ----
  {
    const float* p1 = E1 + ((size_t)(b * H_DIM + wv)) * L_DIM;
    const float* p2 = E2 + ((size_t)(b * H_DIM + wv)) * L_DIM;
#pragma unroll
    for (int it = 0; it < 4; ++it) {
      const int ix = it * 256 + lane * 4;
      *reinterpret_cast<f32x4*>(&e1s[wv][ix]) = *reinterpret_cast<const f32x4*>(p1 + ix);
      *reinterpret_cast<f32x4*>(&e2s[wv][ix]) = *reinterpret_cast<const f32x4*>(p2 + ix);
    }
  }
  __syncthreads();   // the only barrier

  // ---- flash main loop ----
  const int h = wv;
  const int ln15 = lane & 15;      // A-row == B-col
  const int kh = lane >> 4;        // k-group 0..3
  const int jb = kh * 8;           // k-offset within 32-chunk
  const float Rrow = Rr[((size_t)(b * H_DIM + h)) * L_DIM + i0 + ln15];
  const __hip_bfloat16* xb0 =
      xpT + ((size_t)((b * H_DIM + h) * C_DIM + ln15)) * L_DIM;
  const __hip_bfloat16* xb1 = xb0 + 16 * L_DIM;
  const float* p1 = &e1s[h][0];
  const float* p2 = &e2s[h][0];
  const unsigned char* mrow = &msk_b[ln15][0];

  f32x4 acc0 = {0.f, 0.f, 0.f, 0.f};
  f32x4 acc1 = {0.f, 0.f, 0.f, 0.f};
  f32x4 accS = {0.f, 0.f, 0.f, 0.f};
  bf16x8 ones;
#pragma unroll
  for (int e = 0; e < 8; ++e) ones[e] = (__bf16)1.0f;

  // 2-deep prefetch ring, statically indexed via unroll parity (rule #20)
  bf16x8 pf0[2], pf1[2];
  pf0[0] = *reinterpret_cast<const bf16x8*>(xb0 + jb);
  pf1[0] = *reinterpret_cast<const bf16x8*>(xb1 + jb);
  pf0[1] = *reinterpret_cast<const bf16x8*>(xb0 + 32 + jb);
  pf1[1] = *reinterpret_cast<const bf16x8*>(xb1 + 32 + jb);

#pragma unroll 4
  for (int k0 = 0; k0 < L_DIM; k0 += 32) {
    const int sl = (k0 >> 5) & 1;     // compile-time per unrolled copy
    const bf16x8 bb0 = pf0[sl];
    const bf16x8 bb1 = pf1[sl];
    // unguarded prefetch: final over-reads land inside ws (E arrays), unused
    pf0[sl] = *reinterpret_cast<const bf16x8*>(xb0 + k0 + 64 + jb);
    pf1[sl] = *reinterpret_cast<const bf16x8*>(xb1 + k0 + 64 + jb);

    const f32x4 ea = *reinterpret_cast<const f32x4*>(p1 + k0 + jb);
    const f32x4 eb = *reinterpret_cast<const f32x4*>(p1 + k0 + jb + 4);
    const f32x4 fa = *reinterpret_cast<const f32x4*>(p2 + k0 + jb);
    const f32x4 fb = *reinterpret_cast<const f32x4*>(p2 + k0 + jb + 4);
    const unsigned mb = mrow[(k0 >> 3) + kh];   // this lane's 8 mask bits

    bf16x8 af;
#pragma unroll
    for (int e = 0; e < 8; ++e) {
      const float e1v = (e < 4) ? ea[e & 3] : eb[e & 3];
      const float e2v = (e < 4) ? fa[e & 3] : fb[e & 3];
      float v = fmaxf(e1v, e2v * Rrow);          // exp(lrelu(s) - d_i)
      v = (mb & (1u << e)) ? v : 0.0f;
      af[e] = (__bf16)v;
    }
    acc0 = __builtin_amdgcn_mfma_f32_16x16x32_bf16(af, bb0, acc0, 0, 0, 0);
    acc1 = __builtin_amdgcn_mfma_f32_16x16x32_bf16(af, bb1, acc1, 0, 0, 0);
    accS = __builtin_amdgcn_mfma_f32_16x16x32_bf16(af, ones, accS, 0, 0, 0);
  }

  // ---- epilogue: accS[reg] = row sum for row kh*4+reg (any col) ----
#pragma unroll
  for (int reg = 0; reg < 4; ++reg) {
    const float rs = 1.0f / accS[reg];
    float* op = out + ((size_t)(b * L_DIM + i0 + kh * 4 + reg)) * HC + h * C_DIM;
    op[ln15]      = acc0[reg] * rs;
    op[16 + ln15] = acc1[reg] * rs;
  }
}

extern "C" void kernel_launch(void* const* d_in, const int* in_sizes, int n_in,
                              void* d_out, int out_size, void* d_ws, size_t ws_size,
                              hipStream_t stream) {
  (void)in_sizes; (void)n_in; (void)out_size; (void)ws_size;
  const float* x        = (const float*)d_in[0];
  const int*   adj      = (const int*)d_in[1];
  const float* W        = (const float*)d_in[2];
  const float* bias     = (const float*)d_in[3];
  const float* att_src  = (const float*)d_in[4];
  const float* att_dst  = (const float*)d_in[5];
  float* out = (float*)d_out;

  char* ws = (char*)d_ws;
  __hip_bfloat16* xpT   = (__hip_bfloat16*)ws;                          // 4 MiB
  float* E1             = (float*)(ws + (size_t)4 * 1024 * 1024);       // 256 KiB
  float* E2             = (float*)(ws + (size_t)4 * 1024 * 1024 + 262144);
  float* Rr             = (float*)(ws + (size_t)4 * 1024 * 1024 + 524288);
  unsigned char* mask_g = (unsigned char*)(ws + (size_t)4 * 1024 * 1024 + 786432); // 2 MiB

  hipLaunchKernelGGL(proj_mask_kernel, dim3((B_DIM * L_DIM) / TI), dim3(256), 0, stream,
                     x, W, bias, att_src, att_dst, adj, xpT, E1, E2, Rr, mask_g);
  hipLaunchKernelGGL(gat_attn_kernel, dim3((B_DIM * L_DIM) / TI), dim3(256), 0, stream,
                     mask_g, xpT, E1, E2, Rr, out);
}

// Round 5
// 69.925 us; speedup vs baseline: 1.9953x; 1.0107x over previous
//
#include <hip/hip_runtime.h>
#include <hip/hip_bf16.h>

typedef __bf16 bf16x8 __attribute__((ext_vector_type(8)));
typedef float f32x4 __attribute__((ext_vector_type(4)));

#define B_DIM 16
#define L_DIM 1024
#define H_DIM 4
#define C_DIM 32
#define HC 128
#define TI 16
#define MASK_PITCH 128   // bytes per (b,i) row of packed adjacency
#define WPITCH 136       // bf16 elems; 272B rows -> 16B-aligned, reads at LDS BW floor

// ---------------------------------------------------------------------------
// Kernel 1: adjacency -> bitmask, pure streaming (the HBM-bound pass).
// Thread = (row, 64-j segment): 16 independent dwordx4, lane-local bit-pack
// (adj values are exactly {0,1}), diagonal folded in, one 8B store.
// No LDS, no cross-lane ops -> full MLP, should run at HBM/L3 BW.
// ---------------------------------------------------------------------------
__global__ __launch_bounds__(256) void mask_pack_kernel(
    const int* __restrict__ adj, unsigned char* __restrict__ mask_g)
{
  const int t = threadIdx.x;
  const int row = blockIdx.x * 16 + (t >> 4);   // global row over B*L
  const int seg = t & 15;
  const int i = row & (L_DIM - 1);              // diag column for this row
  const int* ap = adj + (size_t)row * L_DIM + seg * 64;

  int4 av[16];
#pragma unroll
  for (int q = 0; q < 16; ++q)
    av[q] = *reinterpret_cast<const int4*>(ap + q * 4);

  unsigned lo = 0u, hi = 0u;
#pragma unroll
  for (int bq = 0; bq < 8; ++bq) {
    const int4 u = av[2 * bq], w = av[2 * bq + 1];
    unsigned bbits = (unsigned)u.x | ((unsigned)u.y << 1) |
                     ((unsigned)u.z << 2) | ((unsigned)u.w << 3) |
                     ((unsigned)w.x << 4) | ((unsigned)w.y << 5) |
                     ((unsigned)w.z << 6) | ((unsigned)w.w << 7);
    const int j0 = seg * 64 + bq * 8;
    const unsigned d = (unsigned)(i - j0);
    if (d < 8u) bbits |= (1u << d);             // diagonal folded in
    if (bq < 4) lo |= bbits << (8 * bq);
    else        hi |= bbits << (8 * (bq - 4));
  }
  *reinterpret_cast<uint2*>(mask_g + (size_t)row * MASK_PITCH + seg * 8) =
      make_uint2(lo, hi);
}

// ---------------------------------------------------------------------------
// Kernel 2: projection via MFMA (xp.T = W @ x.T), 536 MFLOP.
//   Lane mapping identical to the verified attn usage:
//     A-frag: row m = l&15, k = (l>>4)*8+e   (A = W, m -> n)
//     B-frag: col   = l&15, k = (l>>4)*8+e   (B = x.T, col -> x-row)
//     D:      col = l&15 (x-row), row = (l>>4)*4+reg (n-offset)
//   x staged hi/lo (x = hi + lo in bf16) -> 2 MFMAs per W-frag, halving
//   bf16-input error. Epilogue: +bias, bf16 xpT store (transposed layout),
//   a_src/a_dst from fp32 acc (lane-local FMA + shfl_xor 16/32), E1/E2/Rr.
// Block = 128 thr (2 waves), 32 rows; grid 512; LDS 51KB -> 3 blocks/CU.
// ---------------------------------------------------------------------------
__global__ __launch_bounds__(128) void proj_kernel(
    const float* __restrict__ x, const float* __restrict__ W,
    const float* __restrict__ bias, const float* __restrict__ att_src,
    const float* __restrict__ att_dst, __hip_bfloat16* __restrict__ xpT,
    float* __restrict__ E1, float* __restrict__ E2, float* __restrict__ Rr)
{
  __shared__ __align__(16) __bf16 Wlds[128 * WPITCH];  // [n][k]
  __shared__ __align__(16) __bf16 xh[32 * WPITCH];     // [r][k] hi
  __shared__ __align__(16) __bf16 xl[32 * WPITCH];     // [r][k] lo
  const int t = threadIdx.x;
  const int w = t >> 6;           // wave 0/1 -> rows w*16..+15
  const int lane = t & 63;
  const int r0 = blockIdx.x * 32;

  // ---- stage W (bf16): 16384 elems, 8/thread/pass, coalesced ----
#pragma unroll
  for (int p = 0; p < 16; ++p) {
    const int idx = p * 1024 + t * 8;
    const int n = idx >> 7, k = idx & 127;
    const f32x4 a = *reinterpret_cast<const f32x4*>(W + idx);
    const f32x4 b = *reinterpret_cast<const f32x4*>(W + idx + 4);
    bf16x8 v;
#pragma unroll
    for (int e = 0; e < 4; ++e) { v[e] = (__bf16)a[e]; v[e + 4] = (__bf16)b[e]; }
    *reinterpret_cast<bf16x8*>(&Wlds[n * WPITCH + k]) = v;
  }
  // ---- stage x hi/lo: 32x128 elems ----
#pragma unroll
  for (int p = 0; p < 4; ++p) {
    const int idx = p * 1024 + t * 8;
    const int r = idx >> 7, k = idx & 127;
    const float* xp_ = x + (size_t)(r0 + r) * 128 + k;
    const f32x4 a = *reinterpret_cast<const f32x4*>(xp_);
    const f32x4 b = *reinterpret_cast<const f32x4*>(xp_ + 4);
    bf16x8 vh, vl;
#pragma unroll
    for (int e = 0; e < 4; ++e) {
      const float fa = a[e], fb = b[e];
      vh[e] = (__bf16)fa;          vh[e + 4] = (__bf16)fb;
      vl[e] = (__bf16)(fa - (float)vh[e]);
      vl[e + 4] = (__bf16)(fb - (float)vh[e + 4]);
    }
    *reinterpret_cast<bf16x8*>(&xh[r * WPITCH + k]) = vh;
    *reinterpret_cast<bf16x8*>(&xl[r * WPITCH + k]) = vl;
  }
  __syncthreads();

  // ---- MFMA core: 8 n-chunks x 4 k-chunks x (hi+lo) = 64 MFMAs/wave ----
  const int rr = lane & 15;
  const int g8 = (lane >> 4) * 8;
  f32x4 acc[8] = {};
#pragma unroll
  for (int kk = 0; kk < 4; ++kk) {
    const int ko = kk * 32 + g8;
    const bf16x8 bh = *reinterpret_cast<const bf16x8*>(&xh[(w * 16 + rr) * WPITCH + ko]);
    const bf16x8 bl = *reinterpret_cast<const bf16x8*>(&xl[(w * 16 + rr) * WPITCH + ko]);
#pragma unroll
    for (int nc = 0; nc < 8; ++nc) {
      const bf16x8 af = *reinterpret_cast<const bf16x8*>(&Wlds[(nc * 16 + rr) * WPITCH + ko]);
      acc[nc] = __builtin_amdgcn_mfma_f32_16x16x32_bf16(af, bh, acc[nc], 0, 0, 0);
      acc[nc] = __builtin_amdgcn_mfma_f32_16x16x32_bf16(af, bl, acc[nc], 0, 0, 0);
    }
  }

  // ---- epilogue ----
  const int q4 = (lane >> 4) * 4;
  const int grow = r0 + w * 16 + rr;
  const int bb = grow >> 10;
  const int lg = grow & 1023;
  float asum[4] = {0.f, 0.f, 0.f, 0.f};
  float adsum[4] = {0.f, 0.f, 0.f, 0.f};
#pragma unroll
  for (int nc = 0; nc < 8; ++nc) {
    const int n0 = nc * 16 + q4;
    const f32x4 bv = *reinterpret_cast<const f32x4*>(bias + n0);
    const f32x4 sv = *reinterpret_cast<const f32x4*>(att_src + n0);
    const f32x4 dv = *reinterpret_cast<const f32x4*>(att_dst + n0);
    const int h = nc >> 1;
#pragma unroll
    for (int reg = 0; reg < 4; ++reg) {
      const float v = acc[nc][reg] + bv[reg];
      const int n = n0 + reg;
      xpT[((size_t)bb * 128 + n) * 1024 + lg] = __float2bfloat16(v);
      asum[h]  = fmaf(v, sv[reg], asum[h]);
      adsum[h] = fmaf(v, dv[reg], adsum[h]);
    }
  }
#pragma unroll
  for (int h = 0; h < 4; ++h) {
    asum[h]  += __shfl_xor(asum[h], 16);
    asum[h]  += __shfl_xor(asum[h], 32);
    adsum[h] += __shfl_xor(adsum[h], 16);
    adsum[h] += __shfl_xor(adsum[h], 32);
  }
  if ((lane >> 4) == 0) {
#pragma unroll
    for (int h = 0; h < 4; ++h) {
      const size_t o = ((size_t)bb * 4 + h) * 1024 + lg;
      E1[o] = __expf(asum[h]);
      E2[o] = __expf(0.2f * asum[h]);
      Rr[o] = __expf(-0.8f * adsum[h]);
    }
  }
}

// ---------------------------------------------------------------------------
// Kernel 3 (flash attn, unchanged from R4): block = (16-row tile, b),
// wave = head; P = max(E1, E2*R) masked -> bf16 A-frag; 3 MFMAs/iter
// (2 channel halves + ones-B row-sum); lane-local normalize on store.
// ---------------------------------------------------------------------------
__global__ __launch_bounds__(256) void gat_attn_kernel(
    const unsigned char* __restrict__ mask_g,
    const __hip_bfloat16* __restrict__ xpT, const float* __restrict__ E1,
    const float* __restrict__ E2, const float* __restrict__ Rr,
    float* __restrict__ out)
{
  __shared__ __align__(8) unsigned char msk_b[TI][136];
  __shared__ float e1s[H_DIM][L_DIM];
  __shared__ float e2s[H_DIM][L_DIM];

  const int wg  = blockIdx.x;
  const int xcd = wg & 7;
  const int idx = wg >> 3;
  const int b   = xcd * 2 + (idx & 1);
  const int i0  = (idx >> 1) * TI;

  const int t = threadIdx.x;
  const int wv = t >> 6;
  const int lane = t & 63;

  {
    const int r = t >> 4, sg = t & 15;
    const uint2 m = *reinterpret_cast<const uint2*>(
        mask_g + ((size_t)b * L_DIM + i0 + r) * MASK_PITCH + sg * 8);
    *reinterpret_cast<uint2*>(&msk_b[r][sg * 8]) = m;
  }
  {
    const float* p1 = E1 + ((size_t)(b * H_DIM + wv)) * L_DIM;
    const float* p2 = E2 + ((size_t)(b * H_DIM + wv)) * L_DIM;
#pragma unroll
    for (int it = 0; it < 4; ++it) {
      const int ix = it * 256 + lane * 4;
      *reinterpret_cast<f32x4*>(&e1s[wv][ix]) = *reinterpret_cast<const f32x4*>(p1 + ix);
      *reinterpret_cast<f32x4*>(&e2s[wv][ix]) = *reinterpret_cast<const f32x4*>(p2 + ix);
    }
  }
  __syncthreads();

  const int h = wv;
  const int ln15 = lane & 15;
  const int kh = lane >> 4;
  const int jb = kh * 8;
  const float Rrow = Rr[((size_t)(b * H_DIM + h)) * L_DIM + i0 + ln15];
  const __hip_bfloat16* xb0 =
      xpT + ((size_t)((b * H_DIM + h) * C_DIM + ln15)) * L_DIM;
  const __hip_bfloat16* xb1 = xb0 + 16 * L_DIM;
  const float* p1 = &e1s[h][0];
  const float* p2 = &e2s[h][0];
  const unsigned char* mrow = &msk_b[ln15][0];

  f32x4 acc0 = {0.f, 0.f, 0.f, 0.f};
  f32x4 acc1 = {0.f, 0.f, 0.f, 0.f};
  f32x4 accS = {0.f, 0.f, 0.f, 0.f};
  bf16x8 ones;
#pragma unroll
  for (int e = 0; e < 8; ++e) ones[e] = (__bf16)1.0f;

  bf16x8 pf0[2], pf1[2];
  pf0[0] = *reinterpret_cast<const bf16x8*>(xb0 + jb);
  pf1[0] = *reinterpret_cast<const bf16x8*>(xb1 + jb);
  pf0[1] = *reinterpret_cast<const bf16x8*>(xb0 + 32 + jb);
  pf1[1] = *reinterpret_cast<const bf16x8*>(xb1 + 32 + jb);

#pragma unroll 4
  for (int k0 = 0; k0 < L_DIM; k0 += 32) {
    const int sl = (k0 >> 5) & 1;
    const bf16x8 bb0 = pf0[sl];
    const bf16x8 bb1 = pf1[sl];
    pf0[sl] = *reinterpret_cast<const bf16x8*>(xb0 + k0 + 64 + jb);
    pf1[sl] = *reinterpret_cast<const bf16x8*>(xb1 + k0 + 64 + jb);

    const f32x4 ea = *reinterpret_cast<const f32x4*>(p1 + k0 + jb);
    const f32x4 eb = *reinterpret_cast<const f32x4*>(p1 + k0 + jb + 4);
    const f32x4 fa = *reinterpret_cast<const f32x4*>(p2 + k0 + jb);
    const f32x4 fb = *reinterpret_cast<const f32x4*>(p2 + k0 + jb + 4);
    const unsigned mb = mrow[(k0 >> 3) + kh];

    bf16x8 af;
#pragma unroll
    for (int e = 0; e < 8; ++e) {
      const float e1v = (e < 4) ? ea[e & 3] : eb[e & 3];
      const float e2v = (e < 4) ? fa[e & 3] : fb[e & 3];
      float v = fmaxf(e1v, e2v * Rrow);
      v = (mb & (1u << e)) ? v : 0.0f;
      af[e] = (__bf16)v;
    }
    acc0 = __builtin_amdgcn_mfma_f32_16x16x32_bf16(af, bb0, acc0, 0, 0, 0);
    acc1 = __builtin_amdgcn_mfma_f32_16x16x32_bf16(af, bb1, acc1, 0, 0, 0);
    accS = __builtin_amdgcn_mfma_f32_16x16x32_bf16(af, ones, accS, 0, 0, 0);
  }

#pragma unroll
  for (int reg = 0; reg < 4; ++reg) {
    const float rs = 1.0f / accS[reg];
    float* op = out + ((size_t)(b * L_DIM + i0 + kh * 4 + reg)) * HC + h * C_DIM;
    op[ln15]      = acc0[reg] * rs;
    op[16 + ln15] = acc1[reg] * rs;
  }
}

extern "C" void kernel_launch(void* const* d_in, const int* in_sizes, int n_in,
                              void* d_out, int out_size, void* d_ws, size_t ws_size,
                              hipStream_t stream) {
  (void)in_sizes; (void)n_in; (void)out_size; (void)ws_size;
  const float* x        = (const float*)d_in[0];
  const int*   adj      = (const int*)d_in[1];
  const float* W        = (const float*)d_in[2];
  const float* bias     = (const float*)d_in[3];
  const float* att_src  = (const float*)d_in[4];
  const float* att_dst  = (const float*)d_in[5];
  float* out = (float*)d_out;

  char* ws = (char*)d_ws;
  __hip_bfloat16* xpT   = (__hip_bfloat16*)ws;                          // 4 MiB
  float* E1             = (float*)(ws + (size_t)4 * 1024 * 1024);       // 256 KiB
  float* E2             = (float*)(ws + (size_t)4 * 1024 * 1024 + 262144);
  float* Rr             = (float*)(ws + (size_t)4 * 1024 * 1024 + 524288);
  unsigned char* mask_g = (unsigned char*)(ws + (size_t)4 * 1024 * 1024 + 786432); // 2 MiB

  hipLaunchKernelGGL(mask_pack_kernel, dim3(B_DIM * L_DIM / 16), dim3(256), 0, stream,
                     adj, mask_g);
  hipLaunchKernelGGL(proj_kernel, dim3(B_DIM * L_DIM / 32), dim3(128), 0, stream,
                     x, W, bias, att_src, att_dst, xpT, E1, E2, Rr);
  hipLaunchKernelGGL(gat_attn_kernel, dim3(B_DIM * L_DIM / TI), dim3(256), 0, stream,
                     mask_g, xpT, E1, E2, Rr, out);
}

// Round 6
// 61.654 us; speedup vs baseline: 2.2630x; 1.1342x over previous
//
#include <hip/hip_runtime.h>
#include <hip/hip_bf16.h>

typedef __bf16 bf16x8 __attribute__((ext_vector_type(8)));
typedef float f32x4 __attribute__((ext_vector_type(4)));
typedef unsigned int u32x4 __attribute__((ext_vector_type(4)));

#define B_DIM 16
#define L_DIM 1024
#define H_DIM 4
#define C_DIM 32
#define HC 128
#define TI 16
#define WPITCH 136       // bf16 elems; 272B rows -> 16B-aligned LDS rows

static __device__ __forceinline__ unsigned pack_bf16x2(float lo, float hi) {
  __bf16 a = (__bf16)lo, b = (__bf16)hi;
  unsigned short ua, ub;
  __builtin_memcpy(&ua, &a, 2);
  __builtin_memcpy(&ub, &b, 2);
  return (unsigned)ua | ((unsigned)ub << 16);
}

// ---------------------------------------------------------------------------
// Kernel 1: projection via MFMA (xp.T = W @ x.T), verified lane mappings.
//   x staged hi/lo bf16 (error-compensated, 2 MFMAs per W-frag).
//   Outputs: xpT bf16 [b,h,c,l];  E12[b,h,l] = pack(bf16 e1, bf16 e2)
//   with e1=exp(a_src), e2=exp(0.2 a_src);  Rr[b,h,l] = exp(-0.8 a_dst) f32.
// ---------------------------------------------------------------------------
__global__ __launch_bounds__(128) void proj_kernel(
    const float* __restrict__ x, const float* __restrict__ W,
    const float* __restrict__ bias, const float* __restrict__ att_src,
    const float* __restrict__ att_dst, __hip_bfloat16* __restrict__ xpT,
    unsigned* __restrict__ E12, float* __restrict__ Rr)
{
  __shared__ __align__(16) __bf16 Wlds[128 * WPITCH];  // [n][k]
  __shared__ __align__(16) __bf16 xh[32 * WPITCH];     // [r][k] hi
  __shared__ __align__(16) __bf16 xl[32 * WPITCH];     // [r][k] lo
  const int t = threadIdx.x;
  const int w = t >> 6;
  const int lane = t & 63;
  const int r0 = blockIdx.x * 32;

#pragma unroll
  for (int p = 0; p < 16; ++p) {
    const int idx = p * 1024 + t * 8;
    const int n = idx >> 7, k = idx & 127;
    const f32x4 a = *reinterpret_cast<const f32x4*>(W + idx);
    const f32x4 b = *reinterpret_cast<const f32x4*>(W + idx + 4);
    bf16x8 v;
#pragma unroll
    for (int e = 0; e < 4; ++e) { v[e] = (__bf16)a[e]; v[e + 4] = (__bf16)b[e]; }
    *reinterpret_cast<bf16x8*>(&Wlds[n * WPITCH + k]) = v;
  }
#pragma unroll
  for (int p = 0; p < 4; ++p) {
    const int idx = p * 1024 + t * 8;
    const int r = idx >> 7, k = idx & 127;
    const float* xp_ = x + (size_t)(r0 + r) * 128 + k;
    const f32x4 a = *reinterpret_cast<const f32x4*>(xp_);
    const f32x4 b = *reinterpret_cast<const f32x4*>(xp_ + 4);
    bf16x8 vh, vl;
#pragma unroll
    for (int e = 0; e < 4; ++e) {
      const float fa = a[e], fb = b[e];
      vh[e] = (__bf16)fa;          vh[e + 4] = (__bf16)fb;
      vl[e] = (__bf16)(fa - (float)vh[e]);
      vl[e + 4] = (__bf16)(fb - (float)vh[e + 4]);
    }
    *reinterpret_cast<bf16x8*>(&xh[r * WPITCH + k]) = vh;
    *reinterpret_cast<bf16x8*>(&xl[r * WPITCH + k]) = vl;
  }
  __syncthreads();

  const int rr = lane & 15;
  const int g8 = (lane >> 4) * 8;
  f32x4 acc[8] = {};
#pragma unroll
  for (int kk = 0; kk < 4; ++kk) {
    const int ko = kk * 32 + g8;
    const bf16x8 bh = *reinterpret_cast<const bf16x8*>(&xh[(w * 16 + rr) * WPITCH + ko]);
    const bf16x8 bl = *reinterpret_cast<const bf16x8*>(&xl[(w * 16 + rr) * WPITCH + ko]);
#pragma unroll
    for (int nc = 0; nc < 8; ++nc) {
      const bf16x8 af = *reinterpret_cast<const bf16x8*>(&Wlds[(nc * 16 + rr) * WPITCH + ko]);
      acc[nc] = __builtin_amdgcn_mfma_f32_16x16x32_bf16(af, bh, acc[nc], 0, 0, 0);
      acc[nc] = __builtin_amdgcn_mfma_f32_16x16x32_bf16(af, bl, acc[nc], 0, 0, 0);
    }
  }

  const int q4 = (lane >> 4) * 4;
  const int grow = r0 + w * 16 + rr;
  const int bb = grow >> 10;
  const int lg = grow & 1023;
  float asum[4] = {0.f, 0.f, 0.f, 0.f};
  float adsum[4] = {0.f, 0.f, 0.f, 0.f};
#pragma unroll
  for (int nc = 0; nc < 8; ++nc) {
    const int n0 = nc * 16 + q4;
    const f32x4 bv = *reinterpret_cast<const f32x4*>(bias + n0);
    const f32x4 sv = *reinterpret_cast<const f32x4*>(att_src + n0);
    const f32x4 dv = *reinterpret_cast<const f32x4*>(att_dst + n0);
    const int h = nc >> 1;
#pragma unroll
    for (int reg = 0; reg < 4; ++reg) {
      const float v = acc[nc][reg] + bv[reg];
      const int n = n0 + reg;
      xpT[((size_t)bb * 128 + n) * 1024 + lg] = __float2bfloat16(v);
      asum[h]  = fmaf(v, sv[reg], asum[h]);
      adsum[h] = fmaf(v, dv[reg], adsum[h]);
    }
  }
#pragma unroll
  for (int h = 0; h < 4; ++h) {
    asum[h]  += __shfl_xor(asum[h], 16);
    asum[h]  += __shfl_xor(asum[h], 32);
    adsum[h] += __shfl_xor(adsum[h], 16);
    adsum[h] += __shfl_xor(adsum[h], 32);
  }
  if ((lane >> 4) == 0) {
#pragma unroll
    for (int h = 0; h < 4; ++h) {
      const size_t o = ((size_t)bb * 4 + h) * 1024 + lg;
      E12[o] = pack_bf16x2(__expf(asum[h]), __expf(0.2f * asum[h]));
      Rr[o]  = __expf(-0.8f * adsum[h]);
    }
  }
}

// ---------------------------------------------------------------------------
// Kernel 2 (flash attn + inline adj pack):
//   Phase 0a: thread (r,seg) streams 16 INDEPENDENT dwordx4 of adj, packs
//             bits arithmetically (values are {0,1}), diag folded, -> LDS.
//             No ballot -> full MLP; the 64MB adj stream runs at HBM BW
//             across 1024 resident blocks while other blocks compute.
//   Phase 0b: E12 head-slice -> LDS (u32 packed bf16 pair; half the reads).
//   Main: 32 iters K=32: P = max(e1, e2*R) masked -> bf16 A-frag;
//         3 MFMAs (2 channel halves + ones-B row-sum); 4-deep xpT ring.
//   Epilogue: lane-local 1/accS normalize on store.
// ---------------------------------------------------------------------------
__global__ __launch_bounds__(256) void gat_attn_kernel(
    const int* __restrict__ adj, const __hip_bfloat16* __restrict__ xpT,
    const unsigned* __restrict__ E12, const float* __restrict__ Rr,
    float* __restrict__ out)
{
  __shared__ __align__(8) unsigned char msk_b[TI][136];
  __shared__ unsigned e12s[H_DIM][L_DIM];   // 16 KB

  const int wg  = blockIdx.x;
  const int xcd = wg & 7;
  const int idx = wg >> 3;
  const int b   = xcd * 2 + (idx & 1);
  const int i0  = (idx >> 1) * TI;

  const int t = threadIdx.x;
  const int wv = t >> 6;       // wave == head
  const int lane = t & 63;

  // ---- phase 0a: issue 16 independent adj dwordx4 loads ----
  const int r   = t >> 4;
  const int seg = t & 15;
  const int gi  = i0 + r;
  const int* ap = adj + ((size_t)b * L_DIM + gi) * L_DIM + seg * 64;
  int4 av[16];
#pragma unroll
  for (int q = 0; q < 16; ++q)
    av[q] = *reinterpret_cast<const int4*>(ap + q * 4);

  // ---- phase 0b: E12 head-slice -> LDS (overlaps adj loads) ----
  {
    const unsigned* p12 = E12 + ((size_t)(b * H_DIM + wv)) * L_DIM;
#pragma unroll
    for (int it = 0; it < 4; ++it) {
      const int ix = it * 256 + lane * 4;
      *reinterpret_cast<u32x4*>(&e12s[wv][ix]) =
          *reinterpret_cast<const u32x4*>(p12 + ix);
    }
  }

  // ---- pack adj bits (waits on av), store to LDS ----
  {
    unsigned lo = 0u, hi = 0u;
#pragma unroll
    for (int bq = 0; bq < 8; ++bq) {
      const int4 u = av[2 * bq], w2 = av[2 * bq + 1];
      unsigned bbits = (unsigned)u.x | ((unsigned)u.y << 1) |
                       ((unsigned)u.z << 2) | ((unsigned)u.w << 3) |
                       ((unsigned)w2.x << 4) | ((unsigned)w2.y << 5) |
                       ((unsigned)w2.z << 6) | ((unsigned)w2.w << 7);
      const int j0 = seg * 64 + bq * 8;
      const unsigned d = (unsigned)(gi - j0);
      if (d < 8u) bbits |= (1u << d);           // diagonal folded in
      if (bq < 4) lo |= bbits << (8 * bq);
      else        hi |= bbits << (8 * (bq - 4));
    }
    *reinterpret_cast<uint2*>(&msk_b[r][seg * 8]) = make_uint2(lo, hi);
  }
  __syncthreads();   // the only barrier

  // ---- flash main loop ----
  const int h = wv;
  const int ln15 = lane & 15;
  const int kh = lane >> 4;
  const int jb = kh * 8;
  const float Rrow = Rr[((size_t)(b * H_DIM + h)) * L_DIM + i0 + ln15];
  const __hip_bfloat16* xb0 =
      xpT + ((size_t)((b * H_DIM + h) * C_DIM + ln15)) * L_DIM;
  const __hip_bfloat16* xb1 = xb0 + 16 * L_DIM;
  const unsigned* pe = &e12s[h][0];
  const unsigned char* mrow = &msk_b[ln15][0];

  f32x4 acc0 = {0.f, 0.f, 0.f, 0.f};
  f32x4 acc1 = {0.f, 0.f, 0.f, 0.f};
  f32x4 accS = {0.f, 0.f, 0.f, 0.f};
  bf16x8 ones;
#pragma unroll
  for (int e = 0; e < 8; ++e) ones[e] = (__bf16)1.0f;

  // 4-deep prefetch ring (statically indexed via unroll-4 parity)
  bf16x8 pf0[4], pf1[4];
#pragma unroll
  for (int s = 0; s < 4; ++s) {
    pf0[s] = *reinterpret_cast<const bf16x8*>(xb0 + s * 32 + jb);
    pf1[s] = *reinterpret_cast<const bf16x8*>(xb1 + s * 32 + jb);
  }

#pragma unroll 4
  for (int k0 = 0; k0 < L_DIM; k0 += 32) {
    const int sl = (k0 >> 5) & 3;     // compile-time per unrolled copy
    const bf16x8 bb0 = pf0[sl];
    const bf16x8 bb1 = pf1[sl];
    // unguarded prefetch: final over-reads land in ws (E12 region), unused
    pf0[sl] = *reinterpret_cast<const bf16x8*>(xb0 + k0 + 128 + jb);
    pf1[sl] = *reinterpret_cast<const bf16x8*>(xb1 + k0 + 128 + jb);

    const u32x4 ua = *reinterpret_cast<const u32x4*>(pe + k0 + jb);
    const u32x4 ub = *reinterpret_cast<const u32x4*>(pe + k0 + jb + 4);
    const unsigned mb = mrow[(k0 >> 3) + kh];

    bf16x8 af;
#pragma unroll
    for (int e = 0; e < 8; ++e) {
      const unsigned u = (e < 4) ? ua[e & 3] : ub[e & 3];
      const float e1v = __uint_as_float(u << 16);            // bf16 e1 -> f32
      const float e2v = __uint_as_float(u & 0xffff0000u);    // bf16 e2 -> f32
      float v = fmaxf(e1v, e2v * Rrow);     // exp(lrelu(s) - d_i)
      v = (mb & (1u << e)) ? v : 0.0f;
      af[e] = (__bf16)v;
    }
    acc0 = __builtin_amdgcn_mfma_f32_16x16x32_bf16(af, bb0, acc0, 0, 0, 0);
    acc1 = __builtin_amdgcn_mfma_f32_16x16x32_bf16(af, bb1, acc1, 0, 0, 0);
    accS = __builtin_amdgcn_mfma_f32_16x16x32_bf16(af, ones, accS, 0, 0, 0);
  }

#pragma unroll
  for (int reg = 0; reg < 4; ++reg) {
    const float rs = 1.0f / accS[reg];
    float* op = out + ((size_t)(b * L_DIM + i0 + kh * 4 + reg)) * HC + h * C_DIM;
    op[ln15]      = acc0[reg] * rs;
    op[16 + ln15] = acc1[reg] * rs;
  }
}

extern "C" void kernel_launch(void* const* d_in, const int* in_sizes, int n_in,
                              void* d_out, int out_size, void* d_ws, size_t ws_size,
                              hipStream_t stream) {
  (void)in_sizes; (void)n_in; (void)out_size; (void)ws_size;
  const float* x        = (const float*)d_in[0];
  const int*   adj      = (const int*)d_in[1];
  const float* W        = (const float*)d_in[2];
  const float* bias     = (const float*)d_in[3];
  const float* att_src  = (const float*)d_in[4];
  const float* att_dst  = (const float*)d_in[5];
  float* out = (float*)d_out;

  char* ws = (char*)d_ws;
  __hip_bfloat16* xpT = (__hip_bfloat16*)ws;                      // 4 MiB
  unsigned* E12       = (unsigned*)(ws + (size_t)4 * 1024 * 1024); // 256 KiB
  float* Rr           = (float*)(ws + (size_t)4 * 1024 * 1024 + 262144); // 256 KiB

  hipLaunchKernelGGL(proj_kernel, dim3(B_DIM * L_DIM / 32), dim3(128), 0, stream,
                     x, W, bias, att_src, att_dst, xpT, E12, Rr);
  hipLaunchKernelGGL(gat_attn_kernel, dim3(B_DIM * L_DIM / TI), dim3(256), 0, stream,
                     adj, xpT, E12, Rr, out);
}

// Round 7
// 57.714 us; speedup vs baseline: 2.4175x; 1.0683x over previous
//
#include <hip/hip_runtime.h>
#include <hip/hip_bf16.h>

typedef __bf16 bf16x8 __attribute__((ext_vector_type(8)));
typedef _Float16 f16x8 __attribute__((ext_vector_type(8)));
typedef _Float16 f16x2 __attribute__((ext_vector_type(2)));
typedef float f32x4 __attribute__((ext_vector_type(4)));

#define B_DIM 16
#define L_DIM 1024
#define H_DIM 4
#define HC 128
#define TI 16
#define WPITCH 136   // bf16 elems; 272B rows, 16B-aligned

// ---------------------------------------------------------------------------
// Kernel 1: adjacency -> packed bitmask. COALESCED: lane l reads 16B at
// base + l*16 (one wave-load = 1KB contiguous, all lines fully used).
// Lane-local 4-bit pack, then shfl_xor 1/2/4 assemble u32 words (8 lanes
// share word j/32). Diag folded. 8 int4 in flight/wave, 8 blocks/CU.
// ---------------------------------------------------------------------------
__global__ __launch_bounds__(256) void mask_pack_kernel(
    const int* __restrict__ adj, unsigned* __restrict__ mask_g)
{
  const int t = threadIdx.x;
  const int wv = t >> 6, lane = t & 63;
  const int row0 = blockIdx.x * 8 + wv * 2;      // wave handles rows row0, row0+1
  const int* base = adj + (size_t)row0 * L_DIM;

  int4 av[8];
#pragma unroll
  for (int c = 0; c < 4; ++c) {
    av[c]     = *reinterpret_cast<const int4*>(base + c * 256 + lane * 4);
    av[c + 4] = *reinterpret_cast<const int4*>(base + 1024 + c * 256 + lane * 4);
  }

#pragma unroll
  for (int r = 0; r < 2; ++r) {
    const int row = row0 + r;
    const int i = row & (L_DIM - 1);
#pragma unroll
    for (int c = 0; c < 4; ++c) {
      const int4 u = av[r * 4 + c];
      unsigned b4 = (unsigned)u.x | ((unsigned)u.y << 1) |
                    ((unsigned)u.z << 2) | ((unsigned)u.w << 3);
      unsigned p;
      p = __shfl_xor(b4, 1);
      unsigned b8  = (lane & 1) ? (p | (b4 << 4))   : (b4 | (p << 4));
      p = __shfl_xor(b8, 2);
      unsigned b16 = (lane & 2) ? (p | (b8 << 8))   : (b8 | (p << 8));
      p = __shfl_xor(b16, 4);
      unsigned b32 = (lane & 4) ? (p | (b16 << 16)) : (b16 | (p << 16));
      const int widx = c * 8 + (lane >> 3);
      if ((i >> 5) == widx) b32 |= (1u << (i & 31));   // diagonal
      if ((lane & 7) == 0) mask_g[(size_t)row * 32 + widx] = b32;
    }
  }
}

// ---------------------------------------------------------------------------
// Kernel 2: projection via MFMA (verified bf16 hi/lo core), fp16 outputs:
//   xpT f16 [b, h*32+c, l];  E1h = f16(16*exp(a_src));  E2h = f16(exp(0.2 a_src));
//   Rr = f32(16*exp(-0.8 a_dst)).  P' = max(16e1, e2*16R): x16 cancels in
//   softmax, lifts fp16 values out of subnormal range (min ~1.4e-2, max ~1.8e4).
// ---------------------------------------------------------------------------
__global__ __launch_bounds__(128) void proj_kernel(
    const float* __restrict__ x, const float* __restrict__ W,
    const float* __restrict__ bias, const float* __restrict__ att_src,
    const float* __restrict__ att_dst, _Float16* __restrict__ xpT,
    _Float16* __restrict__ E1h, _Float16* __restrict__ E2h,
    float* __restrict__ Rr)
{
  __shared__ __align__(16) __bf16 Wlds[128 * WPITCH];  // [n][k]
  __shared__ __align__(16) __bf16 xh[32 * WPITCH];     // [r][k] hi
  __shared__ __align__(16) __bf16 xl[32 * WPITCH];     // [r][k] lo
  const int t = threadIdx.x;
  const int w = t >> 6;
  const int lane = t & 63;
  const int r0 = blockIdx.x * 32;

#pragma unroll
  for (int p = 0; p < 16; ++p) {
    const int idx = p * 1024 + t * 8;
    const int n = idx >> 7, k = idx & 127;
    const f32x4 a = *reinterpret_cast<const f32x4*>(W + idx);
    const f32x4 b = *reinterpret_cast<const f32x4*>(W + idx + 4);
    bf16x8 v;
#pragma unroll
    for (int e = 0; e < 4; ++e) { v[e] = (__bf16)a[e]; v[e + 4] = (__bf16)b[e]; }
    *reinterpret_cast<bf16x8*>(&Wlds[n * WPITCH + k]) = v;
  }
#pragma unroll
  for (int p = 0; p < 4; ++p) {
    const int idx = p * 1024 + t * 8;
    const int r = idx >> 7, k = idx & 127;
    const float* xp_ = x + (size_t)(r0 + r) * 128 + k;
    const f32x4 a = *reinterpret_cast<const f32x4*>(xp_);
    const f32x4 b = *reinterpret_cast<const f32x4*>(xp_ + 4);
    bf16x8 vh, vl;
#pragma unroll
    for (int e = 0; e < 4; ++e) {
      const float fa = a[e], fb = b[e];
      vh[e] = (__bf16)fa;          vh[e + 4] = (__bf16)fb;
      vl[e] = (__bf16)(fa - (float)vh[e]);
      vl[e + 4] = (__bf16)(fb - (float)vh[e + 4]);
    }
    *reinterpret_cast<bf16x8*>(&xh[r * WPITCH + k]) = vh;
    *reinterpret_cast<bf16x8*>(&xl[r * WPITCH + k]) = vl;
  }
  __syncthreads();

  const int rr = lane & 15;
  const int g8 = (lane >> 4) * 8;
  f32x4 acc[8] = {};
#pragma unroll
  for (int kk = 0; kk < 4; ++kk) {
    const int ko = kk * 32 + g8;
    const bf16x8 bh = *reinterpret_cast<const bf16x8*>(&xh[(w * 16 + rr) * WPITCH + ko]);
    const bf16x8 bl = *reinterpret_cast<const bf16x8*>(&xl[(w * 16 + rr) * WPITCH + ko]);
#pragma unroll
    for (int nc = 0; nc < 8; ++nc) {
      const bf16x8 af = *reinterpret_cast<const bf16x8*>(&Wlds[(nc * 16 + rr) * WPITCH + ko]);
      acc[nc] = __builtin_amdgcn_mfma_f32_16x16x32_bf16(af, bh, acc[nc], 0, 0, 0);
      acc[nc] = __builtin_amdgcn_mfma_f32_16x16x32_bf16(af, bl, acc[nc], 0, 0, 0);
    }
  }

  const int q4 = (lane >> 4) * 4;
  const int grow = r0 + w * 16 + rr;
  const int bb = grow >> 10;
  const int lg = grow & 1023;
  float asum[4] = {0.f, 0.f, 0.f, 0.f};
  float adsum[4] = {0.f, 0.f, 0.f, 0.f};
#pragma unroll
  for (int nc = 0; nc < 8; ++nc) {
    const int n0 = nc * 16 + q4;
    const f32x4 bv = *reinterpret_cast<const f32x4*>(bias + n0);
    const f32x4 sv = *reinterpret_cast<const f32x4*>(att_src + n0);
    const f32x4 dv = *reinterpret_cast<const f32x4*>(att_dst + n0);
    const int h = nc >> 1;
#pragma unroll
    for (int reg = 0; reg < 4; ++reg) {
      const float v = acc[nc][reg] + bv[reg];
      const int n = n0 + reg;
      xpT[((size_t)bb * 128 + n) * 1024 + lg] = (_Float16)v;
      asum[h]  = fmaf(v, sv[reg], asum[h]);
      adsum[h] = fmaf(v, dv[reg], adsum[h]);
    }
  }
#pragma unroll
  for (int h = 0; h < 4; ++h) {
    asum[h]  += __shfl_xor(asum[h], 16);
    asum[h]  += __shfl_xor(asum[h], 32);
    adsum[h] += __shfl_xor(adsum[h], 16);
    adsum[h] += __shfl_xor(adsum[h], 32);
  }
  if ((lane >> 4) == 0) {
#pragma unroll
    for (int h = 0; h < 4; ++h) {
      const size_t o = ((size_t)bb * 4 + h) * 1024 + lg;
      E1h[o] = (_Float16)(16.0f * __expf(asum[h]));
      E2h[o] = (_Float16)__expf(0.2f * asum[h]);
      Rr[o]  = 16.0f * __expf(-0.8f * adsum[h]);
    }
  }
}

// ---------------------------------------------------------------------------
// Kernel 3 (flash attn, packed fp16 inner loop):
//   P'(i,j) = max(16e1_j, e2_j * 16R_i) masked, via v_pk_mul/v_pk_max_f16
//   (2 scores/op) + 256-entry byte->halfmask LUT (x4 bank-replicated) AND.
//   3 f16 MFMAs/iter (2 channel halves + ones row-sum). LUT software-
//   pipelined 1 iter; mask words 1 group ahead; 4-deep xpT ring.
// ---------------------------------------------------------------------------
__global__ __launch_bounds__(256) void gat_attn_kernel(
    const unsigned* __restrict__ mask_g, const _Float16* __restrict__ xpT,
    const _Float16* __restrict__ E1h, const _Float16* __restrict__ E2h,
    const float* __restrict__ Rr, float* __restrict__ out)
{
  __shared__ __align__(16) unsigned e1u[H_DIM][512];    // f16 pairs, 8 KB
  __shared__ __align__(16) unsigned e2u[H_DIM][512];    // 8 KB
  __shared__ __align__(16) uint4 lutlds[4][257];        // 16.1 KB, bank-shifted replicas
  __shared__ __align__(16) unsigned char msk_b[TI][176];

  const int wg  = blockIdx.x;
  const int xcd = wg & 7;
  const int idx = wg >> 3;
  const int b   = xcd * 2 + (idx & 1);
  const int i0  = (idx >> 1) * TI;

  const int t = threadIdx.x;
  const int wv = t >> 6;       // wave == head
  const int lane = t & 63;

  // ---- LUT: byte -> 8 halfword masks (uint4), 4 replicas ----
  {
    const unsigned m0 = ((t & 1) ? 0xFFFFu : 0u) | ((t & 2) ? 0xFFFF0000u : 0u);
    const unsigned m1 = ((t & 4) ? 0xFFFFu : 0u) | ((t & 8) ? 0xFFFF0000u : 0u);
    const unsigned m2 = ((t & 16) ? 0xFFFFu : 0u) | ((t & 32) ? 0xFFFF0000u : 0u);
    const unsigned m3 = ((t & 64) ? 0xFFFFu : 0u) | ((t & 128) ? 0xFFFF0000u : 0u);
    const uint4 ent = {m0, m1, m2, m3};
#pragma unroll
    for (int q = 0; q < 4; ++q) lutlds[q][t] = ent;
  }
  // ---- mask words -> LDS ----
  {
    const int r = t >> 4, sg = t & 15;
    const uint2 m = *reinterpret_cast<const uint2*>(
        mask_g + ((size_t)b * L_DIM + i0 + r) * 32 + sg * 2);
    *reinterpret_cast<uint2*>(&msk_b[r][sg * 8]) = m;
  }
  // ---- E1/E2 head-slices -> LDS ----
  {
    const unsigned* p1 = reinterpret_cast<const unsigned*>(E1h + ((size_t)(b * H_DIM + wv)) * L_DIM);
    const unsigned* p2 = reinterpret_cast<const unsigned*>(E2h + ((size_t)(b * H_DIM + wv)) * L_DIM);
#pragma unroll
    for (int it = 0; it < 2; ++it) {
      const int ix = it * 256 + lane * 4;
      *reinterpret_cast<uint4*>(&e1u[wv][ix]) = *reinterpret_cast<const uint4*>(p1 + ix);
      *reinterpret_cast<uint4*>(&e2u[wv][ix]) = *reinterpret_cast<const uint4*>(p2 + ix);
    }
  }
  __syncthreads();   // the only barrier

  const int h = wv;
  const int ln15 = lane & 15;
  const int kh = lane >> 4;
  const int jb = kh * 8;
  const int lq = lane >> 4;
  const float Rrow = Rr[((size_t)(b * H_DIM + h)) * L_DIM + i0 + ln15];
  const _Float16 rh = (_Float16)Rrow;
  const f16x2 R2 = {rh, rh};
  const _Float16* xb0 = xpT + ((size_t)(b * 128 + h * 32 + ln15)) * 1024;
  const _Float16* xb1 = xb0 + 16 * 1024;

  f32x4 acc0 = {0.f, 0.f, 0.f, 0.f};
  f32x4 acc1 = {0.f, 0.f, 0.f, 0.f};
  f32x4 accS = {0.f, 0.f, 0.f, 0.f};
  f16x8 ones16;
#pragma unroll
  for (int e = 0; e < 8; ++e) ones16[e] = (_Float16)1.0f;

  // 4-deep xpT ring
  uint4 pf0[4], pf1[4];
#pragma unroll
  for (int s = 0; s < 4; ++s) {
    pf0[s] = *reinterpret_cast<const uint4*>(xb0 + s * 32 + jb);
    pf1[s] = *reinterpret_cast<const uint4*>(xb1 + s * 32 + jb);
  }

  // mask-word group prefetch + LUT 1-iter pipeline
  uint4 mw_pf = *reinterpret_cast<const uint4*>(&msk_b[ln15][0]);
  uint4 mwc = mw_pf;
  uint4 lutv = lutlds[lq][(mw_pf.x >> (kh * 8)) & 0xffu];

#pragma unroll 4
  for (int k0 = 0; k0 < L_DIM; k0 += 32) {
    const int tm = (k0 >> 5) & 3;
    if (tm == 0) {
      mwc = mw_pf;
      if (k0 < 896)
        mw_pf = *reinterpret_cast<const uint4*>(&msk_b[ln15][(k0 >> 7) * 16 + 16]);
    }
    // next iter's mask byte -> LUT read (used next iter)
    unsigned mb_n;
    if (tm == 0)      mb_n = (mwc.y >> (kh * 8)) & 0xffu;
    else if (tm == 1) mb_n = (mwc.z >> (kh * 8)) & 0xffu;
    else if (tm == 2) mb_n = (mwc.w >> (kh * 8)) & 0xffu;
    else              mb_n = (mw_pf.x >> (kh * 8)) & 0xffu;
    const uint4 lutv_n = lutlds[lq][mb_n];

    const uint4 u1 = *reinterpret_cast<const uint4*>(&e1u[h][(k0 + jb) >> 1]);
    const uint4 u2 = *reinterpret_cast<const uint4*>(&e2u[h][(k0 + jb) >> 1]);
    const uint4 bb0 = pf0[tm];
    const uint4 bb1 = pf1[tm];
    pf0[tm] = *reinterpret_cast<const uint4*>(xb0 + k0 + 128 + jb);  // over-read safe (ws)
    pf1[tm] = *reinterpret_cast<const uint4*>(xb1 + k0 + 128 + jb);

    const unsigned uu1[4] = {u1.x, u1.y, u1.z, u1.w};
    const unsigned uu2[4] = {u2.x, u2.y, u2.z, u2.w};
    const unsigned ll[4]  = {lutv.x, lutv.y, lutv.z, lutv.w};
    unsigned rr4[4];
#pragma unroll
    for (int q = 0; q < 4; ++q) {
      f16x2 a, ee;
      __builtin_memcpy(&a,  &uu1[q], 4);
      __builtin_memcpy(&ee, &uu2[q], 4);
      const f16x2 pr = ee * R2;                            // v_pk_mul_f16
      const f16x2 mx = __builtin_elementwise_max(a, pr);   // v_pk_max_f16
      unsigned mu;
      __builtin_memcpy(&mu, &mx, 4);
      rr4[q] = mu & ll[q];                                 // mask (0 or keep)
    }
    const uint4 afu = {rr4[0], rr4[1], rr4[2], rr4[3]};
    f16x8 af, b0h, b1h;
    __builtin_memcpy(&af,  &afu, 16);
    __builtin_memcpy(&b0h, &bb0, 16);
    __builtin_memcpy(&b1h, &bb1, 16);
    acc0 = __builtin_amdgcn_mfma_f32_16x16x32_f16(af, b0h, acc0, 0, 0, 0);
    acc1 = __builtin_amdgcn_mfma_f32_16x16x32_f16(af, b1h, acc1, 0, 0, 0);
    accS = __builtin_amdgcn_mfma_f32_16x16x32_f16(af, ones16, accS, 0, 0, 0);
    lutv = lutv_n;
  }

  // ---- epilogue: accS[reg] = row sum (x16 scale cancels in ratio) ----
#pragma unroll
  for (int reg = 0; reg < 4; ++reg) {
    const float rs = 1.0f / accS[reg];
    float* op = out + ((size_t)(b * L_DIM + i0 + kh * 4 + reg)) * HC + h * 32;
    op[ln15]      = acc0[reg] * rs;
    op[16 + ln15] = acc1[reg] * rs;
  }
}

extern "C" void kernel_launch(void* const* d_in, const int* in_sizes, int n_in,
                              void* d_out, int out_size, void* d_ws, size_t ws_size,
                              hipStream_t stream) {
  (void)in_sizes; (void)n_in; (void)out_size; (void)ws_size;
  const float* x        = (const float*)d_in[0];
  const int*   adj      = (const int*)d_in[1];
  const float* W        = (const float*)d_in[2];
  const float* bias     = (const float*)d_in[3];
  const float* att_src  = (const float*)d_in[4];
  const float* att_dst  = (const float*)d_in[5];
  float* out = (float*)d_out;

  char* ws = (char*)d_ws;
  _Float16* xpT   = (_Float16*)ws;                                    // 4 MiB
  _Float16* E1h   = (_Float16*)(ws + (size_t)4 * 1024 * 1024);        // 128 KiB
  _Float16* E2h   = (_Float16*)(ws + (size_t)4 * 1024 * 1024 + 131072);
  float*    Rr    = (float*)(ws + (size_t)4 * 1024 * 1024 + 262144);  // 256 KiB
  unsigned* mask_g = (unsigned*)(ws + (size_t)4 * 1024 * 1024 + 524288); // 2 MiB

  hipLaunchKernelGGL(mask_pack_kernel, dim3(B_DIM * L_DIM / 8), dim3(256), 0, stream,
                     adj, mask_g);
  hipLaunchKernelGGL(proj_kernel, dim3(B_DIM * L_DIM / 32), dim3(128), 0, stream,
                     x, W, bias, att_src, att_dst, xpT, E1h, E2h, Rr);
  hipLaunchKernelGGL(gat_attn_kernel, dim3(B_DIM * L_DIM / TI), dim3(256), 0, stream,
                     mask_g, xpT, E1h, E2h, Rr, out);
}